// Round 6
// baseline (279.605 us; speedup 1.0000x reference)
//
#include <hip/hip_runtime.h>

// LSTMModel: B=4096, T=512, IN=2, H=12, OUT=2, fp32.
// One batch element per wave64; lane = (unit u = lane>>2, gate = lane&3).
// 1024 blocks x 256 threads -> 4096 waves = 4 waves/SIMD.
// v_pk_fma_f32 (tied "+v" accumulator, 3 parallel chains) for the gate dots.
// h broadcast via per-wave private LDS: predicated ds_write_b32 (12 writer
// lanes, banks 0-11, conflict-free) + scalar float readback (same-TBAA as the
// store so the compiler CANNOT hoist the read above the write; it may still
// merge into ds_read_b128). asm memory fences pin the order as belt-and-braces.
// Gate gather (i,f,g,o within a quad) via DPP quad_perm. No barriers.

namespace {
constexpr int H  = 12;
constexpr int T  = 512;
constexpr float LOG2E = 1.4426950408889634f;

typedef float f2 __attribute__((ext_vector_type(2)));
typedef float f4 __attribute__((ext_vector_type(4)));

__device__ __forceinline__ f2 pkfma(f2 a, f2 b, f2 c) {
    asm("v_pk_fma_f32 %0, %1, %2, %0" : "+v"(c) : "v"(a), "v"(b));
    return c;
}
__device__ __forceinline__ f2 pkmul(f2 a, f2 b) {
    f2 d; asm("v_pk_mul_f32 %0, %1, %2" : "=v"(d) : "v"(a), "v"(b)); return d;
}
__device__ __forceinline__ f2 pkadd(f2 a, f2 b) {
    f2 d; asm("v_pk_add_f32 %0, %1, %2" : "=v"(d) : "v"(a), "v"(b)); return d;
}
__device__ __forceinline__ float exp2_(float x) {
    float r; asm("v_exp_f32 %0, %1" : "=v"(r) : "v"(x)); return r;
}
__device__ __forceinline__ float rcp_(float x) { return __builtin_amdgcn_rcpf(x); }
__device__ __forceinline__ void memfence_() { asm volatile("" ::: "memory"); }

template <int CTRL>
__device__ __forceinline__ float dppf(float v) {
    return __int_as_float(__builtin_amdgcn_update_dpp(
        __float_as_int(v), __float_as_int(v), CTRL, 0xF, 0xF, true));
}
constexpr int QP1 = 0x39;  // quad_perm [1,2,3,0]
constexpr int QP2 = 0x4E;  // quad_perm [2,3,0,1]
constexpr int QP3 = 0x93;  // quad_perm [3,0,1,2]
} // namespace

__global__ __launch_bounds__(256, 4) void lstm2_fc_kernel(
    const float* __restrict__ x,      // (4096, 512, 2)
    const float* __restrict__ W_ih0,  // (48, 2)
    const float* __restrict__ W_hh0,  // (48, 12)
    const float* __restrict__ b_ih0,  // (48)
    const float* __restrict__ b_hh0,  // (48)
    const float* __restrict__ W_ih1,  // (48, 12)
    const float* __restrict__ W_hh1,  // (48, 12)
    const float* __restrict__ b_ih1,  // (48)
    const float* __restrict__ b_hh1,  // (48)
    const float* __restrict__ fc_W,   // (2, 12)
    const float* __restrict__ fc_b,   // (2)
    float* __restrict__ out)          // (4096, 2)
{
    const int lane = threadIdx.x & 63;
    const int wid  = __builtin_amdgcn_readfirstlane((int)threadIdx.x >> 6);
    const int b    = blockIdx.x * 4 + wid;       // one element per wave
    const int u    = lane >> 2;                  // unit 0..15 (12 active)
    const int gate = lane & 3;                   // 0:i 1:f 2:g 3:o
    const int uc   = (u < H) ? u : 0;            // clamp idle lanes
    const int r    = gate * H + uc;              // weight row

    // sigmoid for i,f,o; tanh (=2*sigm(2x)-1) for g; exp2 prescale kmul
    // folded into the weights & bias.
    const float pre  = (gate == 2) ? 2.0f : 1.0f;
    const float kmul = -LOG2E * pre;
    const float pa   = 1.0f - pre;
    const float km2  = -2.0f * LOG2E;            // for tanh(c)

    // ---- per-wave private LDS: 16 floats per layer per wave ----
    __shared__ __align__(16) float sm[4 * 32];
    float* smb = &sm[wid * 32];
    const bool writer = (gate == 0) && (u < H);
    float* smw0 = smb + uc;                      // layer-0 writer slot
    float* smw1 = smb + 16 + uc;                 // layer-1 writer slot

    // ---------------- prescaled packed weights -> registers ----------------
    f2 wx, whh0p[6], wih1p[6], whh1p[6];
    wx.x = kmul * W_ih0[r * 2 + 0];
    wx.y = kmul * W_ih0[r * 2 + 1];
#pragma unroll
    for (int k = 0; k < 6; ++k) {
        whh0p[k].x = kmul * W_hh0[r * H + 2 * k];
        whh0p[k].y = kmul * W_hh0[r * H + 2 * k + 1];
        wih1p[k].x = kmul * W_ih1[r * H + 2 * k];
        wih1p[k].y = kmul * W_ih1[r * H + 2 * k + 1];
        whh1p[k].x = kmul * W_hh1[r * H + 2 * k];
        whh1p[k].y = kmul * W_hh1[r * H + 2 * k + 1];
    }
    f2 bias0p, bias1p;
    bias0p.x = kmul * (b_ih0[r] + b_hh0[r]); bias0p.y = 0.0f;
    bias1p.x = kmul * (b_ih1[r] + b_hh1[r]); bias1p.y = 0.0f;

    // ---------------- state ----------------
    float c0 = 0.0f, c1 = 0.0f;
    f2 hp0[6], hq1[6];
#pragma unroll
    for (int k = 0; k < 6; ++k) { hp0[k] = (f2)(0.0f); hq1[k] = (f2)(0.0f); }

    const f4* xb4 = (const f4*)(x + (size_t)b * T * 2);
    f4 xq = xb4[0];

    auto step = [&](f2 xv) {
        // ---- layer 0: 3-chain packed dot (prescaled by kmul) ----
        f2 cA = pkfma(wx, xv, bias0p);
        cA = pkfma(whh0p[0], hp0[0], cA);
        cA = pkfma(whh0p[1], hp0[1], cA);
        f2 cB = pkmul(whh0p[2], hp0[2]);
        cB = pkfma(whh0p[3], hp0[3], cB);
        f2 cC = pkmul(whh0p[4], hp0[4]);
        cC = pkfma(whh0p[5], hp0[5], cC);
        cA = pkadd(cA, cB);
        cA = pkadd(cA, cC);
        const float s0 = fmaf(pre, rcp_(1.0f + exp2_(cA.x + cA.y)), pa);
        const float f0v = dppf<QP1>(s0);
        const float g0v = dppf<QP2>(s0);
        const float o0v = dppf<QP3>(s0);
        c0 = fmaf(f0v, c0, s0 * g0v);            // valid on gate-0 lanes
        const float h0v = o0v * fmaf(2.0f, rcp_(1.0f + exp2_(km2 * c0)), -1.0f);
        if (writer) *smw0 = h0v;                 // publish h0(t), banks 0..11

        // ---- layer 1: whh1 . h1(t-1) chains first (cover LDS round trip) ----
        f2 dA = pkfma(whh1p[0], hq1[0], bias1p);
        dA = pkfma(whh1p[1], hq1[1], dA);
        f2 dB = pkmul(whh1p[2], hq1[2]);
        dB = pkfma(whh1p[3], hq1[3], dB);
        f2 dC = pkmul(whh1p[4], hq1[4]);
        dC = pkfma(whh1p[5], hq1[5], dC);
        // read back h0(t) as SCALAR floats (same TBAA as the store -> the
        // compiler sees the dependence and cannot hoist above the write)
        memfence_();
#pragma unroll
        for (int k = 0; k < 6; ++k) {
            hp0[k].x = smb[2 * k];
            hp0[k].y = smb[2 * k + 1];
        }
        dA = pkfma(wih1p[0], hp0[0], dA);
        dA = pkfma(wih1p[1], hp0[1], dA);
        dB = pkfma(wih1p[2], hp0[2], dB);
        dB = pkfma(wih1p[3], hp0[3], dB);
        dC = pkfma(wih1p[4], hp0[4], dC);
        dC = pkfma(wih1p[5], hp0[5], dC);
        dA = pkadd(dA, dB);
        dA = pkadd(dA, dC);
        const float s1 = fmaf(pre, rcp_(1.0f + exp2_(dA.x + dA.y)), pa);
        const float f1v = dppf<QP1>(s1);
        const float g1v = dppf<QP2>(s1);
        const float o1v = dppf<QP3>(s1);
        c1 = fmaf(f1v, c1, s1 * g1v);
        const float h1v = o1v * fmaf(2.0f, rcp_(1.0f + exp2_(km2 * c1)), -1.0f);
        if (writer) *smw1 = h1v;                 // publish h1(t)
        memfence_();
#pragma unroll
        for (int k = 0; k < 6; ++k) {
            hq1[k].x = smb[16 + 2 * k];
            hq1[k].y = smb[16 + 2 * k + 1];
        }
    };

    for (int tt = 0; tt < T / 2 - 1; ++tt) {
        const f4 xn = xb4[tt + 1];               // prefetch next 2 steps of x
        f2 xa; xa.x = xq.x; xa.y = xq.y;
        step(xa);
        f2 xb; xb.x = xq.z; xb.y = xq.w;
        step(xb);
        xq = xn;
    }
    {   // peeled tail (no prefetch)
        f2 xa; xa.x = xq.x; xa.y = xq.y;
        step(xa);
        f2 xb; xb.x = xq.z; xb.y = xq.w;
        step(xb);
    }

    // ---------------- final FC (lane 0; hq1 holds h1(T-1) pairs) ----------------
    if (lane == 0) {
        float r0 = fc_b[0];
        float r1 = fc_b[1];
#pragma unroll
        for (int k = 0; k < 6; ++k) {
            r0 = fmaf(fc_W[2 * k],     hq1[k].x, r0);
            r0 = fmaf(fc_W[2 * k + 1], hq1[k].y, r0);
            r1 = fmaf(fc_W[H + 2 * k],     hq1[k].x, r1);
            r1 = fmaf(fc_W[H + 2 * k + 1], hq1[k].y, r1);
        }
        float2 res; res.x = r0; res.y = r1;
        *(float2*)(out + (size_t)b * 2) = res;
    }
}

extern "C" void kernel_launch(void* const* d_in, const int* in_sizes, int n_in,
                              void* d_out, int out_size, void* d_ws, size_t ws_size,
                              hipStream_t stream) {
    const float* x     = (const float*)d_in[0];
    const float* W_ih0 = (const float*)d_in[1];
    const float* W_hh0 = (const float*)d_in[2];
    const float* b_ih0 = (const float*)d_in[3];
    const float* b_hh0 = (const float*)d_in[4];
    const float* W_ih1 = (const float*)d_in[5];
    const float* W_hh1 = (const float*)d_in[6];
    const float* b_ih1 = (const float*)d_in[7];
    const float* b_hh1 = (const float*)d_in[8];
    const float* fc_W  = (const float*)d_in[9];
    const float* fc_b  = (const float*)d_in[10];
    float* out = (float*)d_out;

    // 4096 elements, 1 per wave, 4 waves per block -> 1024 blocks
    lstm2_fc_kernel<<<1024, 256, 0, stream>>>(
        x, W_ih0, W_hh0, b_ih0, b_hh0,
        W_ih1, W_hh1, b_ih1, b_hh1, fc_W, fc_b, out);
}